// Round 1
// baseline (466.663 us; speedup 1.0000x reference)
//
#include <hip/hip_runtime.h>
#include <hip/hip_bf16.h>
#include <math.h>

typedef unsigned long long u64;

#define B_DIM 8192
#define S_DIM 4096
#define WPR 64  // 64-bit words per 4096-bit row/col

// ws layout (bytes):
//   [0,     16K)  p1sum[2048] double   (K1 per-block sq*mask partial)
//   [16K,   32K)  p1cnt[2048] u64      (K1 per-block mask count)
//   [32K,   96K)  p3[8192]    double   (K3 per-block sq*count partial)
//   [96K,   96K+4M)  maskbits[B*64] u64
//   [96K+4M, 96K+6M) wbits[S*64]   u64
static const size_t OFF_P1SUM = 0;
static const size_t OFF_P1CNT = 16384;
static const size_t OFF_P3    = 32768;
static const size_t OFF_MB    = 98304;
static const size_t OFF_WB    = OFF_MB + (size_t)B_DIM * WPR * 8;

// ---------------- K1: pack mask bits, accumulate term1 = sum(sq*mask), count ----------------
__global__ __launch_bounds__(256) void k1_pack_mask(
    const float* __restrict__ y, const float* __restrict__ yhat,
    u64* __restrict__ maskbits, double* __restrict__ p1sum, u64* __restrict__ p1cnt)
{
    __shared__ float rs[4];
    __shared__ unsigned rc[4];
    const long long N = (long long)B_DIM * S_DIM;         // 2^25
    const long long stride = (long long)gridDim.x * blockDim.x;  // 2^19 -> 64 uniform iters
    long long i0 = (long long)blockIdx.x * blockDim.x + threadIdx.x;
    float lsum = 0.0f;
    unsigned lcnt = 0;
    for (long long i = i0; i < N; i += stride) {
        float yv = y[i];
        float yh = yhat[i];
        bool nz = (yv != 0.0f);
        u64 bal = __ballot(nz);
        if ((threadIdx.x & 63) == 0) maskbits[i >> 6] = bal;
        float d = yv - yh;
        lsum += nz ? d * d : 0.0f;
        lcnt += nz ? 1u : 0u;
    }
    for (int off = 32; off; off >>= 1) {
        lsum += __shfl_down(lsum, off, 64);
        lcnt += __shfl_down(lcnt, off, 64);
    }
    int wv = threadIdx.x >> 6;
    if ((threadIdx.x & 63) == 0) { rs[wv] = lsum; rc[wv] = lcnt; }
    __syncthreads();
    if (threadIdx.x == 0) {
        double s = (double)rs[0] + (double)rs[1] + (double)rs[2] + (double)rs[3];
        u64 c = (u64)rc[0] + rc[1] + rc[2] + rc[3];
        p1sum[blockIdx.x] = s;
        p1cnt[blockIdx.x] = c;
    }
}

// ---------------- K2: pack W columns to bits: wbits[j][w] bit l = (W[w*64+l][j] != 0) ----------------
__global__ __launch_bounds__(256) void k2_pack_w(
    const float* __restrict__ W, u64* __restrict__ wbits)
{
    __shared__ float tile[64][65];  // +1 pad: conflict-free column reads
    const int j0 = blockIdx.x * 64;
    const int i0 = blockIdx.y * 64;
    const int t = threadIdx.x;
    #pragma unroll
    for (int k = 0; k < 16; ++k) {
        int lin = t + (k << 8);
        int r = lin >> 6, c = lin & 63;
        tile[r][c] = W[(size_t)(i0 + r) * S_DIM + j0 + c];
    }
    __syncthreads();
    const int lane = t & 63;
    const int wv = t >> 6;
    const int w = blockIdx.y;  // i0/64
    for (int jj = wv; jj < 64; jj += 4) {
        u64 bal = __ballot(tile[lane][jj] != 0.0f);
        if (lane == 0) wbits[((size_t)(j0 + jj) << 6) + w] = bal;
    }
}

// ---------------- K3: hot loop — popcount(mask_row & W_col) weighted by sq ----------------
__global__ __launch_bounds__(256) void k3_main(
    const float* __restrict__ y, const float* __restrict__ yhat,
    const u64* __restrict__ maskbits, const u64* __restrict__ wbits,
    double* __restrict__ p3)
{
    __shared__ u64 mT[64][64];  // [w][row]  32KB, transposed for contiguous b128 reads
    __shared__ u64 wT[64][64];  // [w][col]  32KB
    const int b0 = blockIdx.x * 64;   // 128 tiles over B
    const int j0 = blockIdx.y * 64;   // 64 tiles over S
    const int t = threadIdx.x;

    #pragma unroll
    for (int k = 0; k < 16; ++k) {
        int lin = t + (k << 8);
        int r = lin >> 6, w = lin & 63;   // global read coalesced (w contiguous per row)
        mT[w][r] = maskbits[((size_t)(b0 + r) << 6) + w];
        wT[w][r] = wbits[((size_t)(j0 + r) << 6) + w];
    }
    __syncthreads();

    const int r0 = (t >> 4) << 2;   // 0..60 step 4
    const int c0 = (t & 15) << 2;   // 0..60 step 4
    unsigned cnt[4][4];
    #pragma unroll
    for (int a = 0; a < 4; ++a)
        #pragma unroll
        for (int b = 0; b < 4; ++b) cnt[a][b] = 0;

    #pragma unroll 8
    for (int w = 0; w < 64; ++w) {
        u64 m[4], q[4];
        #pragma unroll
        for (int a = 0; a < 4; ++a) m[a] = mT[w][r0 + a];
        #pragma unroll
        for (int b = 0; b < 4; ++b) q[b] = wT[w][c0 + b];
        #pragma unroll
        for (int a = 0; a < 4; ++a)
            #pragma unroll
            for (int b = 0; b < 4; ++b)
                cnt[a][b] += (unsigned)__popcll(m[a] & q[b]);
    }

    // epilogue: weight counts by sq = (y - yhat)^2 at the 4x4 output positions
    float part = 0.0f;
    #pragma unroll
    for (int a = 0; a < 4; ++a) {
        size_t off = ((size_t)(b0 + r0 + a) << 12) + (size_t)(j0 + c0);
        float4 yv = *(const float4*)(y + off);
        float4 yh = *(const float4*)(yhat + off);
        float d0 = yv.x - yh.x, d1 = yv.y - yh.y, d2 = yv.z - yh.z, d3 = yv.w - yh.w;
        part += d0 * d0 * (float)cnt[a][0];
        part += d1 * d1 * (float)cnt[a][1];
        part += d2 * d2 * (float)cnt[a][2];
        part += d3 * d3 * (float)cnt[a][3];
    }

    for (int off = 32; off; off >>= 1) part += __shfl_down(part, off, 64);
    __syncthreads();                     // all waves done with mT before aliasing it
    float* red = (float*)&mT[0][0];
    if ((t & 63) == 0) red[t >> 6] = part;
    __syncthreads();
    if (t == 0) {
        double s = (double)red[0] + (double)red[1] + (double)red[2] + (double)red[3];
        p3[(size_t)blockIdx.y * gridDim.x + blockIdx.x] = s;
    }
}

// ---------------- K4: final reduce + sqrt ----------------
__global__ __launch_bounds__(256) void k4_final(
    const double* __restrict__ p1sum, const u64* __restrict__ p1cnt,
    const double* __restrict__ p3, float* __restrict__ out)
{
    __shared__ double rs1[4], rs3[4];
    __shared__ u64 rcc[4];
    double s1 = 0.0, s3 = 0.0;
    u64 c = 0;
    for (int i = threadIdx.x; i < 2048; i += 256) { s1 += p1sum[i]; c += p1cnt[i]; }
    for (int i = threadIdx.x; i < 8192; i += 256) { s3 += p3[i]; }
    for (int off = 32; off; off >>= 1) {
        s1 += __shfl_down(s1, off, 64);
        s3 += __shfl_down(s3, off, 64);
        c  += __shfl_down(c, off, 64);
    }
    int wv = threadIdx.x >> 6;
    if ((threadIdx.x & 63) == 0) { rs1[wv] = s1; rs3[wv] = s3; rcc[wv] = c; }
    __syncthreads();
    if (threadIdx.x == 0) {
        double S1 = rs1[0] + rs1[1] + rs1[2] + rs1[3];
        double S3 = rs3[0] + rs3[1] + rs3[2] + rs3[3];
        double C  = (double)(rcc[0] + rcc[1] + rcc[2] + rcc[3]);
        double total = S1 + (double)0.1f * S3;   // W entries are exactly float(0.1)
        out[0] = (float)sqrt(total / C + 1e-6);
    }
}

extern "C" void kernel_launch(void* const* d_in, const int* in_sizes, int n_in,
                              void* d_out, int out_size, void* d_ws, size_t ws_size,
                              hipStream_t stream) {
    const float* yhat = (const float*)d_in[0];
    const float* y    = (const float*)d_in[1];
    const float* W    = (const float*)d_in[2];
    char* ws = (char*)d_ws;
    double* p1sum  = (double*)(ws + OFF_P1SUM);
    u64*    p1cnt  = (u64*)(ws + OFF_P1CNT);
    double* p3     = (double*)(ws + OFF_P3);
    u64*    maskbits = (u64*)(ws + OFF_MB);
    u64*    wbits    = (u64*)(ws + OFF_WB);

    k1_pack_mask<<<dim3(2048), dim3(256), 0, stream>>>(y, yhat, maskbits, p1sum, p1cnt);
    k2_pack_w<<<dim3(64, 64), dim3(256), 0, stream>>>(W, wbits);
    k3_main<<<dim3(128, 64), dim3(256), 0, stream>>>(y, yhat, maskbits, wbits, p3);
    k4_final<<<dim3(1), dim3(256), 0, stream>>>(p1sum, p1cnt, p3, (float*)d_out);
}

// Round 2
// 331.789 us; speedup vs baseline: 1.4065x; 1.4065x over previous
//
#include <hip/hip_runtime.h>
#include <math.h>

typedef unsigned long long u64;
typedef __attribute__((ext_vector_type(2))) unsigned long long u64x2;

#define NB 8192
#define NS 4096

// ws layout (bytes):
//   [0,16K)       pcnt[2048] u64      (K1 per-block nonzero count)
//   [16K,32K)     p3[2048]   double   (K3 per-block partial sums)
//   [32K,32K+4M)  maskbitsT[64][8192] u64   (bit-packed mask, word-transposed)
//   [+4M,+6M)     wbitsT[64][4096]    u64   (bit-packed W columns, word-transposed)
static const size_t OFF_CNT = 0;
static const size_t OFF_P3  = 16384;
static const size_t OFF_MB  = 32768;
static const size_t OFF_WB  = OFF_MB + (size_t)64 * 8192 * 8;

// Bit convention: word gw covers elements [gw*64, gw*64+64); bit p of the word
// corresponds to element offset 4*(p&15) + (p>>4). (Order-invariant under the
// AND+popcount contraction as long as K1 and K2 agree.)

// ---------------- K1: pack mask bits (transposed) + count nonzeros ----------------
__global__ __launch_bounds__(256) void k1_pack_mask(
    const float* __restrict__ y, u64* __restrict__ mbT, u64* __restrict__ pcnt)
{
    __shared__ unsigned rc[4];
    const unsigned t = threadIdx.x;
    const unsigned lane = t & 63;
    const float4* y4 = (const float4*)y;
    u64 qi = (u64)blockIdx.x * 256 + t;       // float4 index
    const u64 stride = (u64)2048 * 256;       // 2^19
    unsigned lcnt = 0;
    #pragma unroll 4
    for (int it = 0; it < 16; ++it, qi += stride) {
        float4 v = y4[qi];
        u64 b0 = __ballot(v.x != 0.0f);
        u64 b1 = __ballot(v.y != 0.0f);
        u64 b2 = __ballot(v.z != 0.0f);
        u64 b3 = __ballot(v.w != 0.0f);
        lcnt += (v.x != 0.0f) + (v.y != 0.0f) + (v.z != 0.0f) + (v.w != 0.0f);
        if (lane < 4) {
            unsigned sh = lane << 4;
            u64 word = ((b0 >> sh) & 0xFFFFull)
                     | (((b1 >> sh) & 0xFFFFull) << 16)
                     | (((b2 >> sh) & 0xFFFFull) << 32)
                     | (((b3 >> sh) & 0xFFFFull) << 48);
            u64 gw = ((qi - lane) >> 4) + lane;        // word index, lane=g
            mbT[((gw & 63) << 13) + (gw >> 6)] = word;
        }
    }
    for (int off = 32; off; off >>= 1) lcnt += __shfl_down(lcnt, off, 64);
    if ((t & 63) == 0) rc[t >> 6] = lcnt;
    __syncthreads();
    if (t == 0) pcnt[blockIdx.x] = (u64)rc[0] + rc[1] + rc[2] + rc[3];
}

// ---------------- K2: pack W rows into bit columns (transposed, permuted bit order) ----------------
__global__ __launch_bounds__(256) void k2_pack_w(
    const float* __restrict__ W, u64* __restrict__ wbT)
{
    __shared__ float tile[64][65];
    const int j0 = blockIdx.x * 64;
    const int w  = blockIdx.y;            // W-row block: rows w*64..w*64+63
    const int i0 = w * 64;
    const int t = threadIdx.x;
    #pragma unroll
    for (int k = 0; k < 16; ++k) {
        int lin = t + (k << 8);
        int r = lin >> 6, c = lin & 63;
        tile[r][c] = W[(size_t)(i0 + r) * NS + (j0 + c)];
    }
    __syncthreads();
    const int lane = t & 63;
    const int wv = t >> 6;
    const int pr = ((lane & 15) << 2) + (lane >> 4);   // bit l <-> row offset 4*(l&15)+(l>>4)
    for (int jj = wv; jj < 64; jj += 4) {
        u64 bal = __ballot(tile[pr][jj] != 0.0f);
        if (lane == 0) wbT[((size_t)w << 12) + (j0 + jj)] = bal;
    }
}

// ---------------- K3: 128x128 tile popcount-GEMM, fused sq-weighted epilogue ----------------
__global__ __launch_bounds__(256, 2) void k3_main(
    const float* __restrict__ y, const float* __restrict__ yhat,
    const u64* __restrict__ mbT, const u64* __restrict__ wbT,
    double* __restrict__ p3)
{
    __shared__ alignas(16) u64 mT[32 * 128];   // [w][r], linear chunks
    __shared__ alignas(16) u64 wT[32 * 128];   // [w][c], XOR-swizzled chunks
    const int b0 = blockIdx.x << 7;            // 64 row-tiles
    const int j0 = blockIdx.y << 7;            // 32 col-tiles
    const int t  = threadIdx.x;
    const int r0 = (t >> 4) << 3;              // 8 rows per thread
    const int cj = t & 15;                     // col-group; c0 = cj*8
    const unsigned sx = ((unsigned)cj >> 2) << 4;   // swizzle byte-XOR for q reads

    unsigned cnt[8][8];
    #pragma unroll
    for (int a = 0; a < 8; ++a)
        #pragma unroll
        for (int b = 0; b < 8; ++b) cnt[a][b] = 0;

    char* mB = (char*)mT;
    char* wB = (char*)wT;

    // stage-0 global loads into regs
    u64x2 gm[8], gq[8];
    #pragma unroll
    for (int k = 0; k < 8; ++k) {
        int lin = t + (k << 8);
        int wl = lin >> 6, c2 = lin & 63;
        gm[k] = *(const u64x2*)&mbT[((size_t)wl << 13) + b0 + 2 * c2];
        gq[k] = *(const u64x2*)&wbT[((size_t)wl << 12) + j0 + 2 * c2];
    }

    #pragma unroll 1
    for (int s = 0; s < 2; ++s) {
        // write staged regs -> LDS (wT chunk-swizzled: p = c2 ^ ((c2>>4)&3))
        #pragma unroll
        for (int k = 0; k < 8; ++k) {
            int lin = t + (k << 8);
            int wl = lin >> 6, c2 = lin & 63;
            int p = c2 ^ ((c2 >> 4) & 3);
            *(u64x2*)(mB + (wl << 10) + (c2 << 4)) = gm[k];
            *(u64x2*)(wB + (wl << 10) + (p << 4)) = gq[k];
        }
        __syncthreads();

        if (s == 0) {  // prefetch stage 1 into regs; hides under stage-0 compute
            #pragma unroll
            for (int k = 0; k < 8; ++k) {
                int lin = t + (k << 8);
                int wl = 32 + (lin >> 6), c2 = lin & 63;
                gm[k] = *(const u64x2*)&mbT[((size_t)wl << 13) + b0 + 2 * c2];
                gq[k] = *(const u64x2*)&wbT[((size_t)wl << 12) + j0 + 2 * c2];
            }
        }

        unsigned mo = (unsigned)(r0 << 3);
        unsigned qs = (unsigned)(cj << 6) + sx;
        #pragma unroll 2
        for (int w = 0; w < 32; ++w) {
            u64 m[8], q[8];
            #pragma unroll
            for (int k = 0; k < 4; ++k) {
                u64x2 a = *(const u64x2*)(mB + mo + (k << 4));
                m[2 * k] = a[0]; m[2 * k + 1] = a[1];
                u64x2 b = *(const u64x2*)(wB + (qs ^ (unsigned)(k << 4)));
                q[2 * k] = b[0]; q[2 * k + 1] = b[1];
            }
            #pragma unroll
            for (int aa = 0; aa < 8; ++aa)
                #pragma unroll
                for (int bb = 0; bb < 8; ++bb)
                    cnt[aa][bb] += (unsigned)__builtin_popcountll(m[aa] & q[bb]);
            mo += 1024; qs += 1024;
        }
        __syncthreads();
    }

    // epilogue: part = sum sq * (mask + 0.1*cnt) over this thread's 8x8 patch
    float part = 0.0f;
    const int c0 = cj << 3;
    #pragma unroll
    for (int aa = 0; aa < 8; ++aa) {
        size_t off = ((size_t)(b0 + r0 + aa) << 12) + (size_t)(j0 + c0);
        float ys[8], hs[8];
        *(float4*)&ys[0] = *(const float4*)(y + off);
        *(float4*)&ys[4] = *(const float4*)(y + off + 4);
        *(float4*)&hs[0] = *(const float4*)(yhat + off);
        *(float4*)&hs[4] = *(const float4*)(yhat + off + 4);
        #pragma unroll
        for (int bb = 0; bb < 8; ++bb) {
            float e = ys[bb] - hs[bb];
            float wgt = 0.1f * (float)cnt[aa][bb] + (ys[bb] != 0.0f ? 1.0f : 0.0f);
            part = fmaf(e * e, wgt, part);
        }
    }

    for (int off = 32; off; off >>= 1) part += __shfl_down(part, off, 64);
    float* red = (float*)mT;    // safe: all LDS use done, barrier below
    __syncthreads();
    if ((t & 63) == 0) red[t >> 6] = part;
    __syncthreads();
    if (t == 0)
        p3[(size_t)blockIdx.y * gridDim.x + blockIdx.x] =
            (double)red[0] + (double)red[1] + (double)red[2] + (double)red[3];
}

// ---------------- K4: final reduce + sqrt ----------------
__global__ __launch_bounds__(256) void k4_final(
    const u64* __restrict__ pcnt, const double* __restrict__ p3, float* __restrict__ out)
{
    __shared__ double rs[4];
    __shared__ u64 rcc[4];
    double s3 = 0.0;
    u64 c = 0;
    for (int i = threadIdx.x; i < 2048; i += 256) { s3 += p3[i]; c += pcnt[i]; }
    for (int off = 32; off; off >>= 1) {
        s3 += __shfl_down(s3, off, 64);
        c  += __shfl_down(c, off, 64);
    }
    int wv = threadIdx.x >> 6;
    if ((threadIdx.x & 63) == 0) { rs[wv] = s3; rcc[wv] = c; }
    __syncthreads();
    if (threadIdx.x == 0) {
        double S3 = rs[0] + rs[1] + rs[2] + rs[3];
        double C  = (double)(rcc[0] + rcc[1] + rcc[2] + rcc[3]);
        out[0] = (float)sqrt(S3 / C + 1e-6);
    }
}

extern "C" void kernel_launch(void* const* d_in, const int* in_sizes, int n_in,
                              void* d_out, int out_size, void* d_ws, size_t ws_size,
                              hipStream_t stream) {
    const float* yhat = (const float*)d_in[0];
    const float* y    = (const float*)d_in[1];
    const float* W    = (const float*)d_in[2];
    char* ws = (char*)d_ws;
    u64*    pcnt = (u64*)(ws + OFF_CNT);
    double* p3   = (double*)(ws + OFF_P3);
    u64*    mbT  = (u64*)(ws + OFF_MB);
    u64*    wbT  = (u64*)(ws + OFF_WB);

    k1_pack_mask<<<dim3(2048), dim3(256), 0, stream>>>(y, mbT, pcnt);
    k2_pack_w<<<dim3(64, 64), dim3(256), 0, stream>>>(W, wbT);
    k3_main<<<dim3(64, 32), dim3(256), 0, stream>>>(y, yhat, mbT, wbT, p3);
    k4_final<<<dim3(1), dim3(256), 0, stream>>>(pcnt, p3, (float*)d_out);
}